// Round 1
// baseline (480.849 us; speedup 1.0000x reference)
//
#include <hip/hip_runtime.h>

typedef _Float16 f16;
typedef _Float16 f16x8 __attribute__((ext_vector_type(8)));
typedef float f32x4 __attribute__((ext_vector_type(4)));
typedef float f32x16 __attribute__((ext_vector_type(16)));

#define AS1 __attribute__((address_space(1)))
#define AS3 __attribute__((address_space(3)))

// ---- helpers ---------------------------------------------------------------

__device__ __forceinline__ void gload16(const void* g, void* l) {
    // global -> LDS direct copy, 16B per lane. LDS dest must be linear in lane
    // order (wave-uniform base + lane*16) -- our layouts guarantee that.
    __builtin_amdgcn_global_load_lds(
        (const AS1 unsigned*)(unsigned long long)g,
        (AS3 unsigned*)(unsigned)(unsigned long long)l,
        16, 0, 0);
}

__device__ __forceinline__ unsigned pk2(float a, float b) {
    union { f16 h[2]; unsigned u; } c;
    c.h[0] = (f16)a; c.h[1] = (f16)b;
    return c.u;
}

// ---- fp32 -> fp16 cast ------------------------------------------------------

__global__ __launch_bounds__(256) void k_cast(const float* __restrict__ in,
                                              f16* __restrict__ out, int n) {
    int i = (blockIdx.x * 256 + threadIdx.x) * 4;
    if (i + 3 < n) {
        float4 v = *(const float4*)(in + i);
        union { f16 h[4]; ushort4 u; } c;
        c.h[0] = (f16)v.x; c.h[1] = (f16)v.y; c.h[2] = (f16)v.z; c.h[3] = (f16)v.w;
        *(ushort4*)(out + i) = c.u;
    }
}

// ---- RoPE cos/sin table: [s][i], i in 0..31 --------------------------------

__global__ __launch_bounds__(256) void k_tab(float* __restrict__ cosT,
                                             float* __restrict__ sinT) {
    int idx = blockIdx.x * 256 + threadIdx.x;   // 2048*32 total
    int s = idx >> 5, i = idx & 31;
    // inv_freq = 10000^(-2i/64) = exp2(-i * log2(10000)/32)
    float ang = (float)s * exp2f(-(float)i * 0.4152410118609190f);
    cosT[idx] = cosf(ang);
    sinT[idx] = sinf(ang);
}

// ---- GEMM: C[M][N] = A[M][K] * Bt[N][K]^T, fp16 in, OutT out ---------------
// m97 structure: 128x128 tile, BK=64, 4 waves (2x2 of 64x64), 16x16x32 MFMA.

template <typename OutT>
__global__ __launch_bounds__(256) void k_gemm(const f16* __restrict__ A,
                                              const f16* __restrict__ Bt,
                                              OutT* __restrict__ C,
                                              int M, int N, int K) {
    __shared__ f16 As[128 * 64];
    __shared__ f16 Bs[128 * 64];
    const int tid  = threadIdx.x;
    const int m0   = blockIdx.y * 128, n0 = blockIdx.x * 128;
    const int wid  = tid >> 6, lane = tid & 63;
    const int wm   = (wid >> 1) * 64, wn = (wid & 1) * 64;
    const int lr   = lane & 15, lk = lane >> 4;
    const int srow = tid >> 3;          // 0..31
    const int scol = (tid & 7) * 8;     // halfs

    f32x4 acc[4][4] = {};

    const f16* ga = A  + (size_t)(m0 + srow) * K + scol;
    const f16* gb = Bt + (size_t)(n0 + srow) * K + scol;
    f16* la = &As[srow * 64 + scol];
    f16* lb = &Bs[srow * 64 + scol];

    for (int kt = 0; kt < K; kt += 64) {
#pragma unroll
        for (int i = 0; i < 4; i++) {
            gload16(ga + (size_t)(32 * i) * K + kt, la + 32 * i * 64);
            gload16(gb + (size_t)(32 * i) * K + kt, lb + 32 * i * 64);
        }
        __syncthreads();
        f16x8 af[4][2], bf[4][2];
#pragma unroll
        for (int m = 0; m < 4; m++) {
            af[m][0] = *(const f16x8*)&As[(wm + m * 16 + lr) * 64 + lk * 8];
            af[m][1] = *(const f16x8*)&As[(wm + m * 16 + lr) * 64 + 32 + lk * 8];
        }
#pragma unroll
        for (int n = 0; n < 4; n++) {
            bf[n][0] = *(const f16x8*)&Bs[(wn + n * 16 + lr) * 64 + lk * 8];
            bf[n][1] = *(const f16x8*)&Bs[(wn + n * 16 + lr) * 64 + 32 + lk * 8];
        }
#pragma unroll
        for (int m = 0; m < 4; m++)
#pragma unroll
            for (int n = 0; n < 4; n++) {
                acc[m][n] = __builtin_amdgcn_mfma_f32_16x16x32_f16(af[m][0], bf[n][0], acc[m][n], 0, 0, 0);
                acc[m][n] = __builtin_amdgcn_mfma_f32_16x16x32_f16(af[m][1], bf[n][1], acc[m][n], 0, 0, 0);
            }
        __syncthreads();
    }
#pragma unroll
    for (int m = 0; m < 4; m++)
#pragma unroll
        for (int n = 0; n < 4; n++) {
            size_t base = (size_t)(m0 + wm + m * 16 + lk * 4) * N + (n0 + wn + n * 16 + lr);
#pragma unroll
            for (int j = 0; j < 4; j++)
                C[base + (size_t)j * N] = (OutT)acc[m][n][j];
        }
}

// ---- fused RMSNorm + RoPE + QKV split (one wave per (b,s,head)) ------------
// qkv fp16 [B*S][3072]; writes Q[b][h][s][64], K[b][kh][s][64], Vt[b][kh][64][S]

__global__ __launch_bounds__(256) void k_qkv_post(const f16* __restrict__ qkv,
                                                  const float* __restrict__ qg,
                                                  const float* __restrict__ kg,
                                                  const float* __restrict__ cosT,
                                                  const float* __restrict__ sinT,
                                                  f16* __restrict__ Q,
                                                  f16* __restrict__ K,
                                                  f16* __restrict__ Vt) {
    const int lane = threadIdx.x & 63;
    const int w    = (blockIdx.x * 256 + threadIdx.x) >> 6;  // 0..4095
    const int TOT  = 2 * 2048 * 48;
    for (int it = w; it < TOT; it += 4096) {
        int bs = it / 48, head = it - bs * 48;
        int b = bs >> 11, s = bs & 2047;
        float v = (float)qkv[(size_t)bs * 3072 + head * 64 + lane];
        if (head < 40) {
            float ss = v * v;
#pragma unroll
            for (int off = 32; off; off >>= 1) ss += __shfl_xor(ss, off);
            float r = rsqrtf(ss * (1.0f / 64.0f) + 1e-6f);
            float g = (head < 32) ? qg[lane] : kg[lane];
            float xn = v * r * g;
            float other = __shfl_xor(xn, 32);
            float cs = cosT[(s << 5) | (lane & 31)];
            float sn = sinT[(s << 5) | (lane & 31)];
            float ro = (lane < 32) ? -other : other;
            float o  = xn * cs + ro * sn;
            if (head < 32)
                Q[((size_t)(b * 32 + head) * 2048 + s) * 64 + lane] = (f16)o;
            else
                K[((size_t)(b * 8 + head - 32) * 2048 + s) * 64 + lane] = (f16)o;
        } else {
            Vt[((size_t)(b * 8 + head - 40) * 64 + lane) * 2048 + s] = (f16)v;
        }
    }
}

// ---- flash attention, causal, GQA ------------------------------------------
// 1 wave = 32 q rows, KV tile 32. Swapped QK^T: St[kv][q] = mfma32(Kfrag, Qfrag).
// PV: ctx^T[d][q] = mfma32(Vtfrag, Pfrag). Softmax lane-local per q (col = lane&31).

__global__ __launch_bounds__(256) void k_attn(const f16* __restrict__ Q,
                                              const f16* __restrict__ Kb,
                                              const f16* __restrict__ Vt,
                                              f16* __restrict__ ctx) {
    __shared__ unsigned ct[4][32][32];   // per-wave [q 32][d 64 as 32 dwords]
    const int wid = threadIdx.x >> 6, lane = threadIdx.x & 63;
    const int lq = lane & 31, hi = lane >> 5;
    const int bh = blockIdx.y, b = bh >> 5, h = bh & 31, kh = h >> 2;
    const int q0 = blockIdx.x * 128 + wid * 32;

    const f16* Qp = Q  + ((size_t)(b * 32 + h) * 2048 + q0) * 64;
    const f16* Kp = Kb + ((size_t)(b * 8 + kh) * 2048) * 64;
    const f16* Vp = Vt + ((size_t)(b * 8 + kh) * 64) * 2048;

    f16x8 qf[4];
#pragma unroll
    for (int c = 0; c < 4; c++)
        qf[c] = *(const f16x8*)&Qp[lq * 64 + c * 16 + hi * 8];

    f32x16 o0 = {}, o1 = {};
    float mrun = -3e38f, lrun = 0.0f;
    const int ntiles = (q0 >> 5) + 1;

    for (int kt = 0; kt < ntiles; ++kt) {
        const int k0 = kt << 5;
        f32x16 st = {};
#pragma unroll
        for (int c = 0; c < 4; c++) {
            f16x8 kf = *(const f16x8*)&Kp[(size_t)(k0 + lq) * 64 + c * 16 + hi * 8];
            st = __builtin_amdgcn_mfma_f32_32x32x16_f16(kf, qf[c], st, 0, 0, 0);
        }
        const bool last = (kt == ntiles - 1);
        float sc[16];
        float tmax = -3e38f;
#pragma unroll
        for (int r = 0; r < 16; r++) {
            int kv = k0 + (r & 3) + ((r >> 2) << 3) + (hi << 2);
            float vv = st[r] * 0.125f;
            if (last && kv > q0 + lq) vv = -3e38f;
            sc[r] = vv;
            tmax = fmaxf(tmax, vv);
        }
        tmax = fmaxf(tmax, __shfl_xor(tmax, 32));
        float mnew  = fmaxf(mrun, tmax);
        float alpha = __expf(mrun - mnew);
        mrun = mnew;
        lrun *= alpha;
        o0 = o0 * alpha;
        o1 = o1 * alpha;

        unsigned pkd[8];
        float ps = 0.0f;
#pragma unroll
        for (int j = 0; j < 8; j++) {
            float p0 = __expf(sc[2 * j]     - mnew);
            float p1 = __expf(sc[2 * j + 1] - mnew);
            ps += p0 + p1;
            pkd[j] = pk2(p0, p1);
        }
        lrun += ps;

        unsigned oth[8];
#pragma unroll
        for (int j = 0; j < 8; j++) oth[j] = __shfl_xor(pkd[j], 32);

#pragma unroll
        for (int c = 0; c < 2; c++) {
            unsigned m0_ = hi ? pkd[4 * c + 2] : pkd[4 * c];
            unsigned m1_ = hi ? pkd[4 * c + 3] : pkd[4 * c + 1];
            unsigned t0_ = hi ? oth[4 * c + 2] : oth[4 * c];
            unsigned t1_ = hi ? oth[4 * c + 3] : oth[4 * c + 1];
            union { unsigned u[4]; f16x8 v; } pb;
            pb.u[0] = hi ? t0_ : m0_;
            pb.u[1] = hi ? t1_ : m1_;
            pb.u[2] = hi ? m0_ : t0_;
            pb.u[3] = hi ? m1_ : t1_;
            f16x8 v0 = *(const f16x8*)&Vp[(size_t)lq        * 2048 + k0 + c * 16 + hi * 8];
            f16x8 v1 = *(const f16x8*)&Vp[(size_t)(32 + lq) * 2048 + k0 + c * 16 + hi * 8];
            o0 = __builtin_amdgcn_mfma_f32_32x32x16_f16(v0, pb.v, o0, 0, 0, 0);
            o1 = __builtin_amdgcn_mfma_f32_32x32x16_f16(v1, pb.v, o1, 0, 0, 0);
        }
    }

    float lt  = lrun + __shfl_xor(lrun, 32);
    float inv = 1.0f / lt;

#pragma unroll
    for (int r = 0; r < 16; r += 2) {
        int d0 = (r & 3) + ((r >> 2) << 3) + (hi << 2);
        ct[wid][lq][d0 >> 1]        = pk2(o0[r] * inv, o0[r + 1] * inv);
        ct[wid][lq][(d0 >> 1) + 16] = pk2(o1[r] * inv, o1[r + 1] * inv);
    }
    __syncthreads();

    const size_t obase = ((size_t)b * 2048 + q0) * 2048 + h * 64;  // halfs
#pragma unroll
    for (int i = 0; i < 4; i++) {
        int cid = i * 64 + lane;
        int row = cid >> 3, c8 = cid & 7;
        uint4 val = *(const uint4*)&ct[wid][row][c8 * 4];
        *(uint4*)(ctx + obase + (size_t)row * 2048 + c8 * 8) = val;
    }
}

// ---- launcher ---------------------------------------------------------------

extern "C" void kernel_launch(void* const* d_in, const int* in_sizes, int n_in,
                              void* d_out, int out_size, void* d_ws, size_t ws_size,
                              hipStream_t stream) {
    const float* x     = (const float*)d_in[0];
    const float* w_qkv = (const float*)d_in[1];
    const float* w_out = (const float*)d_in[2];
    const float* qg    = (const float*)d_in[3];
    const float* kg    = (const float*)d_in[4];
    float* out = (float*)d_out;
    char* ws = (char*)d_ws;

    float* cosT = (float*)(ws);                 // 262144 B
    float* sinT = (float*)(ws + 262144);        // 262144 B
    f16* Xh     = (f16*)(ws + 524288);          // 16777216 B
    f16* Wqkvh  = (f16*)(ws + 17301504);        // 12582912 B
    f16* Wouth  = (f16*)(ws + 29884416);        // 8388608 B
    f16* QKVh   = (f16*)(ws + 38273024);        // 25165824 B
    f16* Qh     = (f16*)(ws + 63438848);        // 16777216 B
    f16* Kh     = (f16*)(ws + 80216064);        // 4194304 B
    f16* Vth    = (f16*)(ws + 84410368);        // 4194304 B
    f16* Ctxh   = (f16*)(ws + 88604672);        // 16777216 B  (end ~100.5 MiB)

    k_cast<<<8388608 / 1024, 256, 0, stream>>>(x, Xh, 8388608);
    k_cast<<<6291456 / 1024, 256, 0, stream>>>(w_qkv, Wqkvh, 6291456);
    k_cast<<<4194304 / 1024, 256, 0, stream>>>(w_out, Wouth, 4194304);
    k_tab<<<256, 256, 0, stream>>>(cosT, sinT);

    // qkv = x @ w_qkv^T : M=4096, N=3072, K=2048
    k_gemm<f16><<<dim3(3072 / 128, 4096 / 128), 256, 0, stream>>>(Xh, Wqkvh, QKVh, 4096, 3072, 2048);

    k_qkv_post<<<1024, 256, 0, stream>>>(QKVh, qg, kg, cosT, sinT, Qh, Kh, Vth);

    // attention: grid (S/128 q-tiles, B*HQ)
    k_attn<<<dim3(2048 / 128, 64), 256, 0, stream>>>(Qh, Kh, Vth, Ctxh);

    // out = ctx @ w_out^T : M=4096, N=2048, K=2048
    k_gemm<float><<<dim3(2048 / 128, 4096 / 128), 256, 0, stream>>>(Ctxh, Wouth, out, 4096, 2048, 2048);
}

// Round 3
// 324.773 us; speedup vs baseline: 1.4806x; 1.4806x over previous
//
#include <hip/hip_runtime.h>

typedef _Float16 f16;
typedef __fp16 fp16x2 __attribute__((ext_vector_type(2)));
typedef _Float16 f16x8 __attribute__((ext_vector_type(8)));
typedef float f32x4 __attribute__((ext_vector_type(4)));
typedef float f32x16 __attribute__((ext_vector_type(16)));

#define AS1 __attribute__((address_space(1)))
#define AS3 __attribute__((address_space(3)))

#define SCALE_L2E 0.18033688011112042f   // 0.125 * log2(e)

// ---- helpers ---------------------------------------------------------------

__device__ __forceinline__ void gload16(const void* g, void* l) {
    __builtin_amdgcn_global_load_lds(
        (const AS1 unsigned*)(unsigned long long)g,
        (AS3 unsigned*)(unsigned)(unsigned long long)l,
        16, 0, 0);
}

__device__ __forceinline__ unsigned pk2(float a, float b) {
    union { fp16x2 v; unsigned u; } c;
    c.v = __builtin_amdgcn_cvt_pkrtz(a, b);
    return c.u;
}

// ---- fp32 -> fp16 cast ------------------------------------------------------

__global__ __launch_bounds__(256) void k_cast(const float* __restrict__ in,
                                              f16* __restrict__ out, int n) {
    int i = (blockIdx.x * 256 + threadIdx.x) * 4;
    if (i + 3 < n) {
        float4 v = *(const float4*)(in + i);
        union { f16 h[4]; ushort4 u; } c;
        c.h[0] = (f16)v.x; c.h[1] = (f16)v.y; c.h[2] = (f16)v.z; c.h[3] = (f16)v.w;
        *(ushort4*)(out + i) = c.u;
    }
}

// ---- RoPE cos/sin table: [s][i], i in 0..31 --------------------------------

__global__ __launch_bounds__(256) void k_tab(float* __restrict__ cosT,
                                             float* __restrict__ sinT) {
    int idx = blockIdx.x * 256 + threadIdx.x;   // 2048*32 total
    int s = idx >> 5, i = idx & 31;
    float ang = (float)s * exp2f(-(float)i * 0.4152410118609190f);
    cosT[idx] = cosf(ang);
    sinT[idx] = sinf(ang);
}

// ---- GEMM: C[M][N] = A[M][K] * Bt[N][K]^T, fp16 in, OutT out ---------------

template <typename OutT>
__global__ __launch_bounds__(256) void k_gemm(const f16* __restrict__ A,
                                              const f16* __restrict__ Bt,
                                              OutT* __restrict__ C,
                                              int M, int N, int K) {
    __shared__ f16 As[128 * 64];
    __shared__ f16 Bs[128 * 64];
    const int tid  = threadIdx.x;
    const int m0   = blockIdx.y * 128, n0 = blockIdx.x * 128;
    const int wid  = tid >> 6, lane = tid & 63;
    const int wm   = (wid >> 1) * 64, wn = (wid & 1) * 64;
    const int lr   = lane & 15, lk = lane >> 4;
    const int srow = tid >> 3;
    const int scol = (tid & 7) * 8;

    f32x4 acc[4][4] = {};

    const f16* ga = A  + (size_t)(m0 + srow) * K + scol;
    const f16* gb = Bt + (size_t)(n0 + srow) * K + scol;
    f16* la = &As[srow * 64 + scol];
    f16* lb = &Bs[srow * 64 + scol];

    for (int kt = 0; kt < K; kt += 64) {
#pragma unroll
        for (int i = 0; i < 4; i++) {
            gload16(ga + (size_t)(32 * i) * K + kt, la + 32 * i * 64);
            gload16(gb + (size_t)(32 * i) * K + kt, lb + 32 * i * 64);
        }
        __syncthreads();
        f16x8 af[4][2], bf[4][2];
#pragma unroll
        for (int m = 0; m < 4; m++) {
            af[m][0] = *(const f16x8*)&As[(wm + m * 16 + lr) * 64 + lk * 8];
            af[m][1] = *(const f16x8*)&As[(wm + m * 16 + lr) * 64 + 32 + lk * 8];
        }
#pragma unroll
        for (int n = 0; n < 4; n++) {
            bf[n][0] = *(const f16x8*)&Bs[(wn + n * 16 + lr) * 64 + lk * 8];
            bf[n][1] = *(const f16x8*)&Bs[(wn + n * 16 + lr) * 64 + 32 + lk * 8];
        }
#pragma unroll
        for (int m = 0; m < 4; m++)
#pragma unroll
            for (int n = 0; n < 4; n++) {
                acc[m][n] = __builtin_amdgcn_mfma_f32_16x16x32_f16(af[m][0], bf[n][0], acc[m][n], 0, 0, 0);
                acc[m][n] = __builtin_amdgcn_mfma_f32_16x16x32_f16(af[m][1], bf[n][1], acc[m][n], 0, 0, 0);
            }
        __syncthreads();
    }
#pragma unroll
    for (int m = 0; m < 4; m++)
#pragma unroll
        for (int n = 0; n < 4; n++) {
            size_t base = (size_t)(m0 + wm + m * 16 + lk * 4) * N + (n0 + wn + n * 16 + lr);
#pragma unroll
            for (int j = 0; j < 4; j++)
                C[base + (size_t)j * N] = (OutT)acc[m][n][j];
        }
}

// ---- fused RMSNorm + RoPE + QKV split ---------------------------------------

__global__ __launch_bounds__(256) void k_qkv_post(const f16* __restrict__ qkv,
                                                  const float* __restrict__ qg,
                                                  const float* __restrict__ kg,
                                                  const float* __restrict__ cosT,
                                                  const float* __restrict__ sinT,
                                                  f16* __restrict__ Q,
                                                  f16* __restrict__ K,
                                                  f16* __restrict__ Vt) {
    const int lane = threadIdx.x & 63;
    const int w    = (blockIdx.x * 256 + threadIdx.x) >> 6;
    const int TOT  = 2 * 2048 * 48;
    for (int it = w; it < TOT; it += 4096) {
        int bs = it / 48, head = it - bs * 48;
        int b = bs >> 11, s = bs & 2047;
        float v = (float)qkv[(size_t)bs * 3072 + head * 64 + lane];
        if (head < 40) {
            float ss = v * v;
#pragma unroll
            for (int off = 32; off; off >>= 1) ss += __shfl_xor(ss, off);
            float r = rsqrtf(ss * (1.0f / 64.0f) + 1e-6f);
            float g = (head < 32) ? qg[lane] : kg[lane];
            float xn = v * r * g;
            float other = __shfl_xor(xn, 32);
            float cs = cosT[(s << 5) | (lane & 31)];
            float sn = sinT[(s << 5) | (lane & 31)];
            float ro = (lane < 32) ? -other : other;
            float o  = xn * cs + ro * sn;
            if (head < 32)
                Q[((size_t)(b * 32 + head) * 2048 + s) * 64 + lane] = (f16)o;
            else
                K[((size_t)(b * 8 + head - 32) * 2048 + s) * 64 + lane] = (f16)o;
        } else {
            Vt[((size_t)(b * 8 + head - 40) * 64 + lane) * 2048 + s] = (f16)v;
        }
    }
}

// ---- flash attention, causal, GQA ------------------------------------------
// 1 wave = one 32-row q-block at a time; each wave handles the PAIR (j, 63-j)
// so every wave does exactly 65 KV tiles (perfect static balance).
// Swapped QK^T: St[kv][q] = mfma32(Kfrag, Qfrag); softmax lane-local per q.

__device__ __forceinline__ void attn_qblock(int qb, int lq, int hi,
        const f16* __restrict__ Qbase, const f16* __restrict__ Kp,
        const f16* __restrict__ Vp, f16* __restrict__ ctxbase) {
    const int q0 = qb * 32;

    f16x8 qf[4];
#pragma unroll
    for (int c = 0; c < 4; c++)
        qf[c] = *(const f16x8*)&Qbase[(size_t)(q0 + lq) * 64 + c * 16 + hi * 8];

    f32x16 o0 = {}, o1 = {};
    float mrun = -1e30f, lrun = 0.0f;

    f16x8 kf[4];
#pragma unroll
    for (int c = 0; c < 4; c++)
        kf[c] = *(const f16x8*)&Kp[(size_t)lq * 64 + c * 16 + hi * 8];

    for (int kt = 0; kt <= qb; ++kt) {
        const int k0 = kt << 5;
        f32x16 st = {};
#pragma unroll
        for (int c = 0; c < 4; c++)
            st = __builtin_amdgcn_mfma_f32_32x32x16_f16(kf[c], qf[c], st, 0, 0, 0);

        // V for this tile (independent of QK result)
        f16x8 v0[2], v1[2];
#pragma unroll
        for (int c = 0; c < 2; c++) {
            v0[c] = *(const f16x8*)&Vp[(size_t)lq        * 2048 + k0 + c * 16 + hi * 8];
            v1[c] = *(const f16x8*)&Vp[(size_t)(32 + lq) * 2048 + k0 + c * 16 + hi * 8];
        }
        // prefetch K for next tile
        if (kt < qb) {
            const int kn = (kt + 1) << 5;
#pragma unroll
            for (int c = 0; c < 4; c++)
                kf[c] = *(const f16x8*)&Kp[(size_t)(kn + lq) * 64 + c * 16 + hi * 8];
        }

        float tmax = -1e30f;
        if (kt == qb) {      // diagonal tile: causal mask
#pragma unroll
            for (int r = 0; r < 16; r++) {
                int kvl = (r & 3) + ((r >> 2) << 3) + (hi << 2);
                float v = (kvl > lq) ? -1e30f : st[r] * SCALE_L2E;
                st[r] = v;
                tmax = fmaxf(tmax, v);
            }
        } else {             // bulk tile: no mask
#pragma unroll
            for (int r = 0; r < 16; r++) {
                float v = st[r] * SCALE_L2E;
                st[r] = v;
                tmax = fmaxf(tmax, v);
            }
        }
        tmax = fmaxf(tmax, __shfl_xor(tmax, 32));

        // defer-max (T13): only rescale when the running max grew by >8 (log2)
        if (__any(tmax > mrun + 8.0f)) {
            float mnew  = fmaxf(mrun, tmax);
            float alpha = __builtin_amdgcn_exp2f(mrun - mnew);
            mrun = mnew;
            lrun *= alpha;
            o0 = o0 * alpha;
            o1 = o1 * alpha;
        }

        unsigned pkd[8];
        float ps0 = 0.0f, ps1 = 0.0f;
#pragma unroll
        for (int j = 0; j < 8; j++) {
            float p0 = __builtin_amdgcn_exp2f(st[2 * j]     - mrun);
            float p1 = __builtin_amdgcn_exp2f(st[2 * j + 1] - mrun);
            ps0 += p0; ps1 += p1;
            pkd[j] = pk2(p0, p1);
        }
        lrun += ps0 + ps1;

        unsigned oth[8];
#pragma unroll
        for (int j = 0; j < 8; j++) oth[j] = __shfl_xor(pkd[j], 32);

#pragma unroll
        for (int c = 0; c < 2; c++) {
            unsigned m0_ = hi ? pkd[4 * c + 2] : pkd[4 * c];
            unsigned m1_ = hi ? pkd[4 * c + 3] : pkd[4 * c + 1];
            unsigned t0_ = hi ? oth[4 * c + 2] : oth[4 * c];
            unsigned t1_ = hi ? oth[4 * c + 3] : oth[4 * c + 1];
            union { unsigned u[4]; f16x8 v; } pb;
            pb.u[0] = hi ? t0_ : m0_;
            pb.u[1] = hi ? t1_ : m1_;
            pb.u[2] = hi ? m0_ : t0_;
            pb.u[3] = hi ? m1_ : t1_;
            o0 = __builtin_amdgcn_mfma_f32_32x32x16_f16(v0[c], pb.v, o0, 0, 0, 0);
            o1 = __builtin_amdgcn_mfma_f32_32x32x16_f16(v1[c], pb.v, o1, 0, 0, 0);
        }
    }

    float lt  = lrun + __shfl_xor(lrun, 32);
    float inv = 1.0f / lt;
    unsigned* row = (unsigned*)(ctxbase + (size_t)(q0 + lq) * 2048);
#pragma unroll
    for (int g = 0; g < 4; g++) {
        uint2 a, bq;
        a.x  = pk2(o0[4 * g]     * inv, o0[4 * g + 1] * inv);
        a.y  = pk2(o0[4 * g + 2] * inv, o0[4 * g + 3] * inv);
        *(uint2*)(row + 2 * hi + 4 * g) = a;
        bq.x = pk2(o1[4 * g]     * inv, o1[4 * g + 1] * inv);
        bq.y = pk2(o1[4 * g + 2] * inv, o1[4 * g + 3] * inv);
        *(uint2*)(row + 16 + 2 * hi + 4 * g) = bq;
    }
}

__global__ __launch_bounds__(256) void k_attn(const f16* __restrict__ Q,
                                              const f16* __restrict__ Kb,
                                              const f16* __restrict__ Vt,
                                              f16* __restrict__ ctx) {
    const int wid = threadIdx.x >> 6, lane = threadIdx.x & 63;
    const int lq = lane & 31, hi = lane >> 5;
    const int bh = blockIdx.y, b = bh >> 5, h = bh & 31, kh = h >> 2;
    const int pj = blockIdx.x * 4 + wid;          // pair index 0..31

    const f16* Qbase   = Q  + ((size_t)(b * 32 + h) * 2048) * 64;
    const f16* Kp      = Kb + ((size_t)(b * 8 + kh) * 2048) * 64;
    const f16* Vp      = Vt + ((size_t)(b * 8 + kh) * 64) * 2048;
    f16*       ctxbase = ctx + (size_t)b * 2048 * 2048 + h * 64;

    attn_qblock(pj,      lq, hi, Qbase, Kp, Vp, ctxbase);   // light half
    attn_qblock(63 - pj, lq, hi, Qbase, Kp, Vp, ctxbase);   // heavy half
}

// ---- launcher ---------------------------------------------------------------

extern "C" void kernel_launch(void* const* d_in, const int* in_sizes, int n_in,
                              void* d_out, int out_size, void* d_ws, size_t ws_size,
                              hipStream_t stream) {
    const float* x     = (const float*)d_in[0];
    const float* w_qkv = (const float*)d_in[1];
    const float* w_out = (const float*)d_in[2];
    const float* qg    = (const float*)d_in[3];
    const float* kg    = (const float*)d_in[4];
    float* out = (float*)d_out;
    char* ws = (char*)d_ws;

    float* cosT = (float*)(ws);
    float* sinT = (float*)(ws + 262144);
    f16* Xh     = (f16*)(ws + 524288);
    f16* Wqkvh  = (f16*)(ws + 17301504);
    f16* Wouth  = (f16*)(ws + 29884416);
    f16* QKVh   = (f16*)(ws + 38273024);
    f16* Qh     = (f16*)(ws + 63438848);
    f16* Kh     = (f16*)(ws + 80216064);
    f16* Vth    = (f16*)(ws + 84410368);
    f16* Ctxh   = (f16*)(ws + 88604672);

    k_cast<<<8388608 / 1024, 256, 0, stream>>>(x, Xh, 8388608);
    k_cast<<<6291456 / 1024, 256, 0, stream>>>(w_qkv, Wqkvh, 6291456);
    k_cast<<<4194304 / 1024, 256, 0, stream>>>(w_out, Wouth, 4194304);
    k_tab<<<256, 256, 0, stream>>>(cosT, sinT);

    // qkv = x @ w_qkv^T : M=4096, N=3072, K=2048
    k_gemm<f16><<<dim3(3072 / 128, 4096 / 128), 256, 0, stream>>>(Xh, Wqkvh, QKVh, 4096, 3072, 2048);

    k_qkv_post<<<1024, 256, 0, stream>>>(QKVh, qg, kg, cosT, sinT, Qh, Kh, Vth);

    // attention: 512 blocks, perfectly balanced (65 KV-tiles per wave)
    k_attn<<<dim3(8, 64), 256, 0, stream>>>(Qh, Kh, Vth, Ctxh);

    // out = ctx @ w_out^T : M=4096, N=2048, K=2048
    k_gemm<float><<<dim3(2048 / 128, 4096 / 128), 256, 0, stream>>>(Ctxh, Wouth, out, 4096, 2048, 2048);
}